// Round 1
// baseline (498.421 us; speedup 1.0000x reference)
//
#include <hip/hip_runtime.h>
#include <math.h>

#define NBINS 15

// Zero the workspace accumulators (d_ws is re-poisoned to 0xAA before every
// timed launch, so this must run every call).
__global__ void zero_ws(float* __restrict__ ws, int n) {
    int i = blockIdx.x * blockDim.x + threadIdx.x;
    const int stride = gridDim.x * blockDim.x;
    for (; i < n; i += stride) ws[i] = 0.0f;
}

// One wave (64 lanes) per row. Each lane holds 16 logits in registers
// (4x float4), does butterfly reductions for max / argmax / sum(exp),
// then bins its 16 probs into a per-block LDS sum_conf table via LDS atomics.
// sum_lab / correct / total go straight to global atomics (1 per row each).
__global__ __launch_bounds__(1024, 4) void fused_sce(
    const float* __restrict__ logits, const int* __restrict__ labels,
    float* __restrict__ g_conf, float* __restrict__ g_lab,
    float* __restrict__ g_cor, float* __restrict__ g_tot,
    int N, int C) {
    extern __shared__ float s_conf[];  // C * NBINS floats
    const int tid = threadIdx.x;
    const int nseg = C * NBINS;
    for (int i = tid; i < nseg; i += blockDim.x) s_conf[i] = 0.0f;
    __syncthreads();

    const int lane = tid & 63;
    const int gw = blockIdx.x * (blockDim.x >> 6) + (tid >> 6);
    const int nw = gridDim.x * (blockDim.x >> 6);
    const int nf4 = C >> 2;  // C assumed divisible by 4 (C=1000)

    for (int row = gw; row < N; row += nw) {
        const float4* rp = (const float4*)(logits + (size_t)row * C);
        float4 x[4];
#pragma unroll
        for (int k = 0; k < 4; ++k) {
            const int idx = k * 64 + lane;
            if (idx < nf4) x[k] = rp[idx];
            else x[k] = make_float4(-INFINITY, -INFINITY, -INFINITY, -INFINITY);
        }

        // ---- row max (butterfly over 64 lanes) ----
        float m = -INFINITY;
#pragma unroll
        for (int k = 0; k < 4; ++k)
            m = fmaxf(m, fmaxf(fmaxf(x[k].x, x[k].y), fmaxf(x[k].z, x[k].w)));
#pragma unroll
        for (int off = 32; off > 0; off >>= 1)
            m = fmaxf(m, __shfl_xor(m, off));

        // ---- argmax, first-index tie-break (matches jnp.argmax) ----
        float bv = -INFINITY;
        int bi = 0x7fffffff;
#pragma unroll
        for (int k = 0; k < 4; ++k) {
            const int c0 = (k * 64 + lane) * 4;
            const float xv[4] = {x[k].x, x[k].y, x[k].z, x[k].w};
#pragma unroll
            for (int j = 0; j < 4; ++j) {
                const float v = xv[j];
                if (v > bv || (v == bv && (c0 + j) < bi)) { bv = v; bi = c0 + j; }
            }
        }
#pragma unroll
        for (int off = 32; off > 0; off >>= 1) {
            const float ov = __shfl_xor(bv, off);
            const int oi = __shfl_xor(bi, off);
            if (ov > bv || (ov == bv && oi < bi)) { bv = ov; bi = oi; }
        }

        // ---- sum(exp(x - m)), overwrite x with exp values ----
        float s = 0.0f;
#pragma unroll
        for (int k = 0; k < 4; ++k) {
            x[k].x = __expf(x[k].x - m);  // exp(-inf)=0 for masked slots
            x[k].y = __expf(x[k].y - m);
            x[k].z = __expf(x[k].z - m);
            x[k].w = __expf(x[k].w - m);
            s += (x[k].x + x[k].y) + (x[k].z + x[k].w);
        }
#pragma unroll
        for (int off = 32; off > 0; off >>= 1)
            s += __shfl_xor(s, off);
        const float inv = 1.0f / s;

        const int label = labels[row];

        // ---- bin probs, accumulate conf into LDS; lab via global atomic ----
#pragma unroll
        for (int k = 0; k < 4; ++k) {
            const int idx = k * 64 + lane;
            if (idx < nf4) {
                const int c0 = idx * 4;
                const float ev[4] = {x[k].x, x[k].y, x[k].z, x[k].w};
#pragma unroll
                for (int j = 0; j < 4; ++j) {
                    const float p = ev[j] * inv;
                    if (p > 0.0f) {  // conf==0 falls in no bin (ref drops it)
                        int b = (int)ceilf(p * 15.0f) - 1;
                        b = b < 0 ? 0 : (b > 14 ? 14 : b);
                        atomicAdd(&s_conf[(c0 + j) * NBINS + b], p);
                        if (c0 + j == label)
                            atomicAdd(&g_lab[(c0 + j) * NBINS + b], 1.0f);
                    }
                }
            }
        }
        if (lane == 0) {
            atomicAdd(&g_tot[label], 1.0f);
            if (bi == label) atomicAdd(&g_cor[label], 1.0f);
        }
    }

    // ---- flush per-block LDS table to global (skip zeros) ----
    __syncthreads();
    for (int i = tid; i < nseg; i += blockDim.x) {
        const float v = s_conf[i];
        if (v != 0.0f) atomicAdd(&g_conf[i], v);
    }
}

__global__ void finalize_k(const float* __restrict__ g_conf,
                           const float* __restrict__ g_lab,
                           const float* __restrict__ g_cor,
                           const float* __restrict__ g_tot,
                           float* __restrict__ out, int N, int C) {
    const int c = blockIdx.x * blockDim.x + threadIdx.x;
    if (c >= C) return;
    float t = 0.0f;
#pragma unroll
    for (int b = 0; b < NBINS; ++b)
        t += fabsf(g_conf[c * NBINS + b] - g_lab[c * NBINS + b]);
    out[c] = t / (float)N;           // per_class_sce
    out[C + c] = g_cor[c] / g_tot[c];  // classes_acc
}

extern "C" void kernel_launch(void* const* d_in, const int* in_sizes, int n_in,
                              void* d_out, int out_size, void* d_ws, size_t ws_size,
                              hipStream_t stream) {
    const float* logits = (const float*)d_in[0];
    const int* labels = (const int*)d_in[1];
    const int N = in_sizes[1];                 // 50000
    const int C = in_sizes[0] / in_sizes[1];   // 1000

    float* ws = (float*)d_ws;
    float* g_conf = ws;                          // C*NBINS
    float* g_lab = ws + (size_t)C * NBINS;       // C*NBINS
    float* g_cor = ws + (size_t)2 * C * NBINS;   // C
    float* g_tot = g_cor + C;                    // C
    const int tot_ws = 2 * C * NBINS + 2 * C;

    zero_ws<<<64, 256, 0, stream>>>(ws, tot_ws);

    const int block = 1024;
    const int grid = 512;  // 2 blocks/CU target (LDS 60KB/block)
    const size_t lds_bytes = (size_t)C * NBINS * sizeof(float);
    fused_sce<<<grid, block, lds_bytes, stream>>>(logits, labels, g_conf, g_lab,
                                                  g_cor, g_tot, N, C);

    finalize_k<<<(C + 255) / 256, 256, 0, stream>>>(g_conf, g_lab, g_cor, g_tot,
                                                    (float*)d_out, N, C);
}

// Round 4
// 394.226 us; speedup vs baseline: 1.2643x; 1.2643x over previous
//
#include <hip/hip_runtime.h>
#include <math.h>

#define NBINS 15
#define BIN0_HI (1.0f / 15.0f)  // bin 0 covers (0, 1/15]; searchsorted 'left' puts p==1/15 in bin 0

__global__ void zero_ws(float* __restrict__ ws, int n) {
    int i = blockIdx.x * blockDim.x + threadIdx.x;
    const int stride = gridDim.x * blockDim.x;
    for (; i < n; i += stride) ws[i] = 0.0f;
}

// ---- Pass A: one wave per row. Fused max+argmax butterfly, then sum-exp
// butterfly. Writes (rowmax, 1/sumexp). Handles sum_lab (1 atomic/row via the
// lane holding the label class), correct/total (lane 0). No LDS.
__global__ __launch_bounds__(256) void row_stats(
    const float* __restrict__ logits, const int* __restrict__ labels,
    float2* __restrict__ rowstats, float* __restrict__ g_lab,
    float* __restrict__ g_cor, float* __restrict__ g_tot, int N, int C) {
    const int lane = threadIdx.x & 63;
    const int gw = blockIdx.x * (blockDim.x >> 6) + (threadIdx.x >> 6);
    const int nw = gridDim.x * (blockDim.x >> 6);
    const int nf4 = C >> 2;

    for (int row = gw; row < N; row += nw) {
        const float4* rp = (const float4*)(logits + (size_t)row * C);
        float4 x[4];
#pragma unroll
        for (int k = 0; k < 4; ++k) {
            const int idx = k * 64 + lane;
            if (idx < nf4) x[k] = rp[idx];
            else x[k] = make_float4(-INFINITY, -INFINITY, -INFINITY, -INFINITY);
        }

        // fused max + argmax (first-index tie-break, matches jnp.argmax)
        float bv = -INFINITY;
        int bi = 0x7fffffff;
#pragma unroll
        for (int k = 0; k < 4; ++k) {
            const int c0 = (k * 64 + lane) * 4;
            const float xv[4] = {x[k].x, x[k].y, x[k].z, x[k].w};
#pragma unroll
            for (int j = 0; j < 4; ++j) {
                const float v = xv[j];
                if (v > bv || (v == bv && (c0 + j) < bi)) { bv = v; bi = c0 + j; }
            }
        }
#pragma unroll
        for (int off = 32; off > 0; off >>= 1) {
            const float ov = __shfl_xor(bv, off);
            const int oi = __shfl_xor(bi, off);
            if (ov > bv || (ov == bv && oi < bi)) { bv = ov; bi = oi; }
        }
        const float m = bv;  // row max value

        // sum(exp(x - m)); overwrite x with exp values
        float s = 0.0f;
#pragma unroll
        for (int k = 0; k < 4; ++k) {
            x[k].x = __expf(x[k].x - m);  // exp(-inf) = 0 for masked slots
            x[k].y = __expf(x[k].y - m);
            x[k].z = __expf(x[k].z - m);
            x[k].w = __expf(x[k].w - m);
            s += (x[k].x + x[k].y) + (x[k].z + x[k].w);
        }
#pragma unroll
        for (int off = 32; off > 0; off >>= 1) s += __shfl_xor(s, off);
        const float inv = 1.0f / s;

        const int label = labels[row];

        // lane holding the label class bins its prob into g_lab
        const int fi = label >> 2;  // float4 slot of the label class
        if ((fi & 63) == lane) {
            const int k = fi >> 6, j = label & 3;
            const float4 v = (k == 0) ? x[0] : (k == 1) ? x[1] : (k == 2) ? x[2] : x[3];
            const float e = (j == 0) ? v.x : (j == 1) ? v.y : (j == 2) ? v.z : v.w;
            const float p = e * inv;
            if (p > 0.0f) {
                int b;
                if (p <= BIN0_HI) b = 0;
                else { b = (int)ceilf(p * 15.0f) - 1; b = b < 1 ? 1 : (b > 14 ? 14 : b); }
                atomicAdd(&g_lab[label * NBINS + b], 1.0f);
            }
        }
        if (lane == 0) {
            rowstats[row] = make_float2(m, inv);
            atomicAdd(&g_tot[label], 1.0f);
            if (bi == label) atomicAdd(&g_cor[label], 1.0f);
        }
    }
}

// ---- Pass B: column-major binning. Thread t owns classes 4t..4t+3, walks a
// row chunk with coalesced float4 loads (logits L3-resident after pass A).
// Bin-0 mass accumulates in registers; p > 1/15 is the wave-voted rare path
// (global atomic). Per-chunk partials written densely — no atomics.
__global__ __launch_bounds__(256) void col_bin(
    const float* __restrict__ logits, const float2* __restrict__ rowstats,
    float* __restrict__ partial, float* __restrict__ g_rare,
    int N, int C, int R) {
    const int t = threadIdx.x;
    const int c0 = t * 4;
    if (c0 >= C) return;
    const int r0 = blockIdx.x * R;
    const int r1 = min(N, r0 + R);

    float a0 = 0.f, a1 = 0.f, a2 = 0.f, a3 = 0.f;
    for (int r = r0; r < r1; ++r) {
        const float4 x = *(const float4*)(logits + (size_t)r * C + c0);
        const float2 st = rowstats[r];  // block-uniform -> scalar-cached
        const float p0 = __expf(x.x - st.x) * st.y;
        const float p1 = __expf(x.y - st.x) * st.y;
        const float p2 = __expf(x.z - st.x) * st.y;
        const float p3 = __expf(x.w - st.x) * st.y;
        const bool s0 = p0 > BIN0_HI, s1 = p1 > BIN0_HI, s2 = p2 > BIN0_HI, s3 = p3 > BIN0_HI;
        a0 += s0 ? 0.f : p0;  // p==0 adds 0 (ref drops conf==0: contributes 0)
        a1 += s1 ? 0.f : p1;
        a2 += s2 ? 0.f : p2;
        a3 += s3 ? 0.f : p3;
        if (__any(s0 | s1 | s2 | s3)) {  // rare: prob > 1/15
            const float pv[4] = {p0, p1, p2, p3};
            const bool sv[4] = {s0, s1, s2, s3};
#pragma unroll
            for (int j = 0; j < 4; ++j) {
                if (sv[j]) {
                    int b = (int)ceilf(pv[j] * 15.0f) - 1;
                    b = b < 1 ? 1 : (b > 14 ? 14 : b);
                    atomicAdd(&g_rare[(c0 + j) * NBINS + b], pv[j]);
                }
            }
        }
    }
    float4 out;
    out.x = a0; out.y = a1; out.z = a2; out.w = a3;
    *(float4*)(partial + (size_t)blockIdx.x * C + c0) = out;
}

// ---- Finalize: one wave per class. Reduce per-chunk bin-0 partials, add
// rare-bin table, emit SCE and accuracy.
__global__ __launch_bounds__(256) void finalize_k(
    const float* __restrict__ partial, const float* __restrict__ g_rare,
    const float* __restrict__ g_lab, const float* __restrict__ g_cor,
    const float* __restrict__ g_tot, float* __restrict__ out,
    int N, int C, int NC) {
    const int lane = threadIdx.x & 63;
    const int c = blockIdx.x * (blockDim.x >> 6) + (threadIdx.x >> 6);
    if (c >= C) return;
    float s = 0.0f;
    for (int i = lane; i < NC; i += 64) s += partial[(size_t)i * C + c];
#pragma unroll
    for (int off = 32; off > 0; off >>= 1) s += __shfl_xor(s, off);
    if (lane == 0) {
        float tsum = fabsf(s + g_rare[c * NBINS] - g_lab[c * NBINS]);
#pragma unroll
        for (int b = 1; b < NBINS; ++b)
            tsum += fabsf(g_rare[c * NBINS + b] - g_lab[c * NBINS + b]);
        out[c] = tsum / (float)N;
        out[C + c] = g_cor[c] / g_tot[c];
    }
}

extern "C" void kernel_launch(void* const* d_in, const int* in_sizes, int n_in,
                              void* d_out, int out_size, void* d_ws, size_t ws_size,
                              hipStream_t stream) {
    const float* logits = (const float*)d_in[0];
    const int* labels = (const int*)d_in[1];
    const int N = in_sizes[1];                 // 50000
    const int C = in_sizes[0] / in_sizes[1];   // 1000

    float* f = (float*)d_ws;
    float2* rowstats = (float2*)f;                    // N float2
    float* g_lab = f + (size_t)2 * N;                 // C*NBINS
    float* g_rare = g_lab + (size_t)C * NBINS;        // C*NBINS
    float* g_cor = g_rare + (size_t)C * NBINS;        // C
    float* g_tot = g_cor + C;                         // C
    float* partial = g_tot + C;                       // NC * C

    // size the chunk count to whatever workspace remains
    const size_t fixed = (size_t)2 * N + (size_t)2 * C * NBINS + (size_t)2 * C;
    long avail = (long)(ws_size / 4) - (long)fixed;
    long ncmax = avail > 0 ? avail / C : 1;
    int NC = (int)(ncmax < 1 ? 1 : (ncmax > 2048 ? 2048 : ncmax));
    if (NC > N) NC = N;
    const int R = (N + NC - 1) / NC;
    NC = (N + R - 1) / R;  // actual chunk count

    zero_ws<<<64, 256, 0, stream>>>(g_lab, 2 * C * NBINS + 2 * C);

    row_stats<<<2048, 256, 0, stream>>>(logits, labels, rowstats, g_lab,
                                        g_cor, g_tot, N, C);

    col_bin<<<NC, 256, 0, stream>>>(logits, rowstats, partial, g_rare, N, C, R);

    finalize_k<<<(C + 3) / 4, 256, 0, stream>>>(partial, g_rare, g_lab, g_cor,
                                                g_tot, (float*)d_out, N, C, NC);
}

// Round 5
// 387.179 us; speedup vs baseline: 1.2873x; 1.0182x over previous
//
#include <hip/hip_runtime.h>
#include <math.h>

#define NBINS 15
#define BIN0_HI (1.0f / 15.0f)  // bin 0 covers (0, 1/15]; searchsorted 'left' puts p==1/15 in bin 0

__global__ void zero_ws(float* __restrict__ ws, int n) {
    int i = blockIdx.x * blockDim.x + threadIdx.x;
    const int stride = gridDim.x * blockDim.x;
    for (; i < n; i += stride) ws[i] = 0.0f;
}

// Single pass over logits. One wave per row (grid-strided). Per row:
// registers hold the full row (16 float4/lane), butterfly max+argmax,
// exp, butterfly sum. Then each lane folds its 16 probs into a PERSISTENT
// per-column register accumulator (lane->column map is row-invariant).
// p > 1/15 (rare for softmax over 1000 classes) goes to global atomics.
// Block epilogue: LDS-reduce the 8 waves' accumulators, write one dense
// per-block partial row. No rowstats array, no second logits read.
__global__ __launch_bounds__(512) void fused_pass(
    const float* __restrict__ logits, const int* __restrict__ labels,
    float* __restrict__ partial, float* __restrict__ g_rare,
    float* __restrict__ g_lab, float* __restrict__ g_cor,
    float* __restrict__ g_tot, int N, int C) {
    extern __shared__ float s_colsum[];  // C floats
    const int tid = threadIdx.x;
    const int lane = tid & 63;
    const int gw = blockIdx.x * (blockDim.x >> 6) + (tid >> 6);
    const int nw = gridDim.x * (blockDim.x >> 6);
    const int nf4 = C >> 2;

    float4 acc[4];
#pragma unroll
    for (int k = 0; k < 4; ++k) acc[k] = make_float4(0.f, 0.f, 0.f, 0.f);

    for (int row = gw; row < N; row += nw) {
        const float4* rp = (const float4*)(logits + (size_t)row * C);
        float4 x[4];
#pragma unroll
        for (int k = 0; k < 4; ++k) {
            const int idx = k * 64 + lane;
            if (idx < nf4) x[k] = rp[idx];
            else x[k] = make_float4(-INFINITY, -INFINITY, -INFINITY, -INFINITY);
        }

        // fused max + argmax (first-index tie-break, matches jnp.argmax)
        float bv = -INFINITY;
        int bi = 0x7fffffff;
#pragma unroll
        for (int k = 0; k < 4; ++k) {
            const int c0 = (k * 64 + lane) * 4;
            const float xv[4] = {x[k].x, x[k].y, x[k].z, x[k].w};
#pragma unroll
            for (int j = 0; j < 4; ++j) {
                const float v = xv[j];
                if (v > bv || (v == bv && (c0 + j) < bi)) { bv = v; bi = c0 + j; }
            }
        }
#pragma unroll
        for (int off = 32; off > 0; off >>= 1) {
            const float ov = __shfl_xor(bv, off);
            const int oi = __shfl_xor(bi, off);
            if (ov > bv || (ov == bv && oi < bi)) { bv = ov; bi = oi; }
        }
        const float m = bv;

        // sum(exp(x - m)); overwrite x with exp values
        float s = 0.0f;
#pragma unroll
        for (int k = 0; k < 4; ++k) {
            x[k].x = __expf(x[k].x - m);  // exp(-inf) = 0 for masked slots
            x[k].y = __expf(x[k].y - m);
            x[k].z = __expf(x[k].z - m);
            x[k].w = __expf(x[k].w - m);
            s += (x[k].x + x[k].y) + (x[k].z + x[k].w);
        }
#pragma unroll
        for (int off = 32; off > 0; off >>= 1) s += __shfl_xor(s, off);
        const float inv = 1.0f / s;

        const int label = labels[row];

        // lane holding the label class bins its prob into g_lab (1 atomic/row)
        const int fi = label >> 2;
        if ((fi & 63) == lane) {
            const int k = fi >> 6, j = label & 3;
            const float4 v = (k == 0) ? x[0] : (k == 1) ? x[1] : (k == 2) ? x[2] : x[3];
            const float e = (j == 0) ? v.x : (j == 1) ? v.y : (j == 2) ? v.z : v.w;
            const float p = e * inv;
            if (p > 0.0f) {
                int b;
                if (p <= BIN0_HI) b = 0;
                else { b = (int)ceilf(p * 15.0f) - 1; b = b < 1 ? 1 : (b > 14 ? 14 : b); }
                atomicAdd(&g_lab[label * NBINS + b], 1.0f);
            }
        }
        if (lane == 0) {
            atomicAdd(&g_tot[label], 1.0f);
            if (bi == label) atomicAdd(&g_cor[label], 1.0f);
        }

        // fold probs into persistent per-column register accumulators.
        // Masked slots have e==0 -> p==0 -> add 0; no idx guard needed.
#pragma unroll
        for (int k = 0; k < 4; ++k) {
            const float p0 = x[k].x * inv, p1 = x[k].y * inv;
            const float p2 = x[k].z * inv, p3 = x[k].w * inv;
            const bool r0 = p0 > BIN0_HI, r1 = p1 > BIN0_HI;
            const bool r2 = p2 > BIN0_HI, r3 = p3 > BIN0_HI;
            acc[k].x += r0 ? 0.f : p0;
            acc[k].y += r1 ? 0.f : p1;
            acc[k].z += r2 ? 0.f : p2;
            acc[k].w += r3 ? 0.f : p3;
            if (__any(r0 | r1 | r2 | r3)) {  // rare: prob > 1/15
                const int c0 = (k * 64 + lane) * 4;
                const float pv[4] = {p0, p1, p2, p3};
                const bool rv[4] = {r0, r1, r2, r3};
#pragma unroll
                for (int j = 0; j < 4; ++j) {
                    if (rv[j]) {
                        int b = (int)ceilf(pv[j] * 15.0f) - 1;
                        b = b < 1 ? 1 : (b > 14 ? 14 : b);
                        atomicAdd(&g_rare[(c0 + j) * NBINS + b], pv[j]);
                    }
                }
            }
        }
    }

    // ---- block epilogue: reduce 8 waves' accumulators via LDS ----
    for (int i = tid; i < C; i += blockDim.x) s_colsum[i] = 0.0f;
    __syncthreads();
#pragma unroll
    for (int k = 0; k < 4; ++k) {
        const int idx = k * 64 + lane;
        if (idx < nf4) {
            const int c0 = idx * 4;
            atomicAdd(&s_colsum[c0 + 0], acc[k].x);
            atomicAdd(&s_colsum[c0 + 1], acc[k].y);
            atomicAdd(&s_colsum[c0 + 2], acc[k].z);
            atomicAdd(&s_colsum[c0 + 3], acc[k].w);
        }
    }
    __syncthreads();
    for (int i = tid; i < C; i += blockDim.x)
        partial[(size_t)blockIdx.x * C + i] = s_colsum[i];
}

// ---- Finalize: one wave per class. Reduce per-block bin-0 partials, add
// rare-bin table, emit SCE and accuracy.
__global__ __launch_bounds__(256) void finalize_k(
    const float* __restrict__ partial, const float* __restrict__ g_rare,
    const float* __restrict__ g_lab, const float* __restrict__ g_cor,
    const float* __restrict__ g_tot, float* __restrict__ out,
    int N, int C, int NC) {
    const int lane = threadIdx.x & 63;
    const int c = blockIdx.x * (blockDim.x >> 6) + (threadIdx.x >> 6);
    if (c >= C) return;
    float s = 0.0f;
    for (int i = lane; i < NC; i += 64) s += partial[(size_t)i * C + c];
#pragma unroll
    for (int off = 32; off > 0; off >>= 1) s += __shfl_xor(s, off);
    if (lane == 0) {
        float tsum = fabsf(s + g_rare[c * NBINS] - g_lab[c * NBINS]);
#pragma unroll
        for (int b = 1; b < NBINS; ++b)
            tsum += fabsf(g_rare[c * NBINS + b] - g_lab[c * NBINS + b]);
        out[c] = tsum / (float)N;
        out[C + c] = g_cor[c] / g_tot[c];
    }
}

extern "C" void kernel_launch(void* const* d_in, const int* in_sizes, int n_in,
                              void* d_out, int out_size, void* d_ws, size_t ws_size,
                              hipStream_t stream) {
    const float* logits = (const float*)d_in[0];
    const int* labels = (const int*)d_in[1];
    const int N = in_sizes[1];                 // 50000
    const int C = in_sizes[0] / in_sizes[1];   // 1000

    float* f = (float*)d_ws;
    float* g_lab = f;                                 // C*NBINS
    float* g_rare = g_lab + (size_t)C * NBINS;        // C*NBINS
    float* g_cor = g_rare + (size_t)C * NBINS;        // C
    float* g_tot = g_cor + C;                         // C
    float* partial = g_tot + C;                       // GRID * C

    // size the block count to workspace (partial = GRID*C floats)
    const size_t fixed = (size_t)2 * C * NBINS + (size_t)2 * C;
    long avail = (long)(ws_size / 4) - (long)fixed;
    long gmax = avail > 0 ? avail / C : 64;
    int GRID = (int)(gmax < 64 ? 64 : (gmax > 1024 ? 1024 : gmax));

    zero_ws<<<64, 256, 0, stream>>>(f, 2 * C * NBINS + 2 * C);

    fused_pass<<<GRID, 512, (size_t)C * sizeof(float), stream>>>(
        logits, labels, partial, g_rare, g_lab, g_cor, g_tot, N, C);

    finalize_k<<<(C + 3) / 4, 256, 0, stream>>>(partial, g_rare, g_lab, g_cor,
                                                g_tot, (float*)d_out, N, C, GRID);
}